// Round 7
// baseline (365.041 us; speedup 1.0000x reference)
//
#include <hip/hip_runtime.h>
#include <stdint.h>
#include <math.h>

typedef __attribute__((ext_vector_type(4))) int i32x4;
typedef __attribute__((ext_vector_type(16))) int i32x16;
typedef __attribute__((ext_vector_type(4))) float f32x4;

constexpr int D_DIM = 1280;   // embedding dim (lin1 K, lin2 N)
constexpr int H_DIM = 5120;   // mlp dim      (lin1 N, lin2 K)

__device__ __forceinline__ void gload_lds16(const void* g, void* l) {
  __builtin_amdgcn_global_load_lds(
      (const __attribute__((address_space(1))) void*)g,
      (__attribute__((address_space(3))) void*)l,
      16, 0, 0);
}

// branchless erf, Abramowitz-Stegun 7.1.26, |eps| <= 1.5e-7
__device__ __forceinline__ float gelu_fast(float h) {
  const float x = h * 0.70710678118f;
  const float ax = fabsf(x);
  const float t = __frcp_rn(__builtin_fmaf(0.3275911f, ax, 1.0f));
  float p = __builtin_fmaf(1.061405429f, t, -1.453152027f);
  p = __builtin_fmaf(p, t, 1.421413741f);
  p = __builtin_fmaf(p, t, -0.284496736f);
  p = __builtin_fmaf(p, t, 0.254829592f);
  p *= t;
  const float e = __expf(-x * x);
  const float erf_ax = __builtin_fmaf(-p, e, 1.0f);
  const float erf_x = copysignf(erf_ax, x);
  return 0.5f * h * (1.0f + erf_x);
}

// ---- pack int32 (sign-extended int8) -> int8 --------------------------------
__global__ void __launch_bounds__(256) k_packw(const int* __restrict__ s1,
                                               const int* __restrict__ s2,
                                               int8_t* __restrict__ out,
                                               long wn) {
  long i = ((long)blockIdx.x * 256 + threadIdx.x) * 16;
  const int* p = (i < wn) ? (s1 + i) : (s2 + (i - wn));
  i32x4 a = *(const i32x4*)(p);
  i32x4 b = *(const i32x4*)(p + 4);
  i32x4 c = *(const i32x4*)(p + 8);
  i32x4 d = *(const i32x4*)(p + 12);
  i32x4 r;
  r.x = (a.x & 255) | ((a.y & 255) << 8) | ((a.z & 255) << 16) | (a.w << 24);
  r.y = (b.x & 255) | ((b.y & 255) << 8) | ((b.z & 255) << 16) | (b.w << 24);
  r.z = (c.x & 255) | ((c.y & 255) << 8) | ((c.z & 255) << 16) | (c.w << 24);
  r.w = (d.x & 255) | ((d.y & 255) << 8) | ((d.z & 255) << 16) | (d.w << 24);
  *(i32x4*)(out + i) = r;
}

__global__ void __launch_bounds__(256) k_pack(const int* __restrict__ in,
                                              int8_t* __restrict__ out,
                                              long n) {
  long i = ((long)blockIdx.x * 256 + threadIdx.x) * 16;
  if (i >= n) return;
  const int* p = in + i;
  i32x4 a = *(const i32x4*)(p);
  i32x4 b = *(const i32x4*)(p + 4);
  i32x4 c = *(const i32x4*)(p + 8);
  i32x4 d = *(const i32x4*)(p + 12);
  i32x4 r;
  r.x = (a.x & 255) | ((a.y & 255) << 8) | ((a.z & 255) << 16) | (a.w << 24);
  r.y = (b.x & 255) | ((b.y & 255) << 8) | ((b.z & 255) << 16) | (b.w << 24);
  r.z = (c.x & 255) | ((c.y & 255) << 8) | ((c.z & 255) << 16) | (c.w << 24);
  r.w = (d.x & 255) | ((d.y & 255) << 8) | ((d.z & 255) << 16) | (d.w << 24);
  *(i32x4*)(out + i) = r;
}

// ---- fused int8 GEMM: 256x256 tile, BK=128B, 8 waves, acc 4x2 of 32x32 ------
// D[r][c] = sum_k P[r][k]*S[c][k]  (both row-major with ld = KDIM, NT GEMM)
// GELU=true  (lin1): P=W1 (r=h), S=x (c=token). Requant+gelu -> int8 Q,
//                    stored Q[token][h] via swizzled-LDS transpose, ld ODIM.
// GELU=false (lin2): P=q (r=token), S=W2 (c=d). fp32 out row-major, ld ODIM.
// CFAST: consecutive blocks share rt (P-panel resident); else share ct.
template <int KDIM, int ODIM, bool GELU, bool CFAST>
__global__ void __launch_bounds__(512, 2)
k_gemm256(const int8_t* __restrict__ P, const int8_t* __restrict__ S,
          const float* __restrict__ bias, const float* __restrict__ ps1,
          const float* __restrict__ ps2, void* __restrict__ Cout,
          int rtiles, int ctiles) {
  constexpr int BKB = 128;
  constexpr int NT = KDIM / BKB;   // 10 (lin1) / 40 (lin2), both even
  // [P buf0 32K][P buf1 32K][S buf0 32K][S buf1 32K]
  __shared__ __align__(16) int8_t smem[131072];

  // ---- block mapping: bijective XCD chunk, panel-resident ordering ----------
  const int nwg = rtiles * ctiles;
  int rt, ct;
  {
    const int bid = blockIdx.x;
    const int q = nwg >> 3, r = nwg & 7, x = bid & 7, l = bid >> 3;
    const int swz = (x < r ? x * (q + 1) : r * (q + 1) + (x - r) * q) + l;
    if (CFAST) { rt = swz / ctiles; ct = swz % ctiles; }
    else       { ct = swz / rtiles; rt = swz % rtiles; }
  }

  const int tid = threadIdx.x;
  const int lane = tid & 63, wid = tid >> 6;
  const int wr = wid >> 2, wc = wid & 3;   // 2 r-waves x 4 c-waves: 128x64 each
  const int r32 = lane & 31, hi5 = lane >> 5;

  // ---- staging: linear LDS dest, inverse-swizzled global source -------------
  const int srow = tid >> 3;                      // 0..63
  const int soff = ((tid & 7) ^ (srow & 7)) << 4;
  const int8_t* Pth = P + (size_t)(rt * 256 + srow) * KDIM + soff;
  const int8_t* Sth = S + (size_t)(ct * 256 + srow) * KDIM + soff;
  const int dT = tid * 16;

  auto STAGE = [&](int buf, int t) {   // 8 gload_lds / thread / K-tile
    const int8_t* gp = Pth + t * BKB;
    const int8_t* gs = Sth + t * BKB;
#pragma unroll
    for (int p = 0; p < 4; ++p)
      gload_lds16(gp + (size_t)(p * 64) * KDIM, smem + buf * 32768 + dT + p * 8192);
#pragma unroll
    for (int p = 0; p < 4; ++p)
      gload_lds16(gs + (size_t)(p * 64) * KDIM,
                  smem + 65536 + buf * 32768 + dT + p * 8192);
  };

  // ---- fragment offsets (XOR-swizzled; conflict-free staging/read pair) -----
  const int fsw = (r32 & 7) << 4;
  const int kq = hi5 << 4;
  int koff[4];
#pragma unroll
  for (int ks = 0; ks < 4; ++ks) koff[ks] = (ks * 32 + kq) ^ fsw;
  const int prow = (wr * 128 + r32) * BKB;   // + i*4096 per 32-row P-frag
  const int srw  = (wc * 64 + r32) * BKB;    // + j*4096 per 32-row S-frag

  i32x16 acc[4][2] = {};

  auto COMPUTE = [&](int buf) {
    const int8_t* Pb = smem + buf * 32768;
    const int8_t* Sb = smem + 65536 + buf * 32768;
#pragma unroll
    for (int ks = 0; ks < 4; ++ks) {
      i32x4 pf[4], sf[2];
#pragma unroll
      for (int i = 0; i < 4; ++i)
        pf[i] = *(const i32x4*)(Pb + prow + i * 4096 + koff[ks]);
#pragma unroll
      for (int j = 0; j < 2; ++j)
        sf[j] = *(const i32x4*)(Sb + srw + j * 4096 + koff[ks]);
      __builtin_amdgcn_s_setprio(1);
#pragma unroll
      for (int i = 0; i < 4; ++i)
#pragma unroll
        for (int j = 0; j < 2; ++j)
          acc[i][j] =
              __builtin_amdgcn_mfma_i32_32x32x32_i8(pf[i], sf[j], acc[i][j], 0, 0, 0);
      __builtin_amdgcn_s_setprio(0);
    }
  };

  // ---- main loop: simple 2-phase dbuf, unroll-2 for static offsets ----------
  STAGE(0, 0);
  __syncthreads();
#pragma unroll 1
  for (int t = 0; t < NT; t += 2) {
    STAGE(1, t + 1);               // NT even: t+1 always valid
    COMPUTE(0);
    __syncthreads();               // buf1 landed; buf0 free
    if (t + 2 < NT) STAGE(0, t + 2);
    COMPUTE(1);
    __syncthreads();
  }

  // ---- epilogue -------------------------------------------------------------
  // 32x32 C/D: col = lane&31, row = (reg&3) + 8*(reg>>2) + 4*(lane>>5)
  if constexpr (GELU) {
    const float s1 = *ps1;
    const float rs = 1.0f / (*ps2);
    int8_t* Q = (int8_t*)Cout;
    int8_t* lb = smem;   // 64 KB: 256 tokens x 256 h, 16B-slot XOR swizzle
#pragma unroll
    for (int i = 0; i < 4; ++i) {
#pragma unroll
      for (int q = 0; q < 4; ++q) {
        const int hl = wr * 128 + i * 32 + q * 8 + hi5 * 4;   // local h base
        const f32x4 bv = *(const f32x4*)(bias + rt * 256 + hl);
#pragma unroll
        for (int j = 0; j < 2; ++j) {
          const int tok = wc * 64 + j * 32 + r32;             // local token
          uint32_t pk = 0;
#pragma unroll
          for (int rr = 0; rr < 4; ++rr) {
            const float h = __builtin_fmaf((float)acc[i][j][q * 4 + rr], s1, bv[rr]);
            float qf = rintf(gelu_fast(h) * rs);
            qf = fminf(127.0f, fmaxf(-128.0f, qf));
            pk |= ((uint32_t)((int)qf & 255)) << (rr * 8);
          }
          const int ad = tok * 256 + ((((hl >> 4) ^ (tok & 7)) << 4)) + (hl & 12);
          *(uint32_t*)(lb + ad) = pk;
        }
      }
    }
    __syncthreads();
    // readback: 8 rounds x (32 rows x 256B), fully coalesced dwordx4 stores
#pragma unroll
    for (int it = 0; it < 8; ++it) {
      const int row = (tid >> 4) + it * 32;
      const int sl = tid & 15;
      i32x4 v = *(const i32x4*)(lb + row * 256 + ((sl ^ (row & 7)) << 4));
      *(i32x4*)(Q + (size_t)(ct * 256 + row) * ODIM + rt * 256 + sl * 16) = v;
    }
  } else {
    const float s1 = *ps1;
    float* O = (float*)Cout;
#pragma unroll
    for (int i = 0; i < 4; ++i) {
#pragma unroll
      for (int j = 0; j < 2; ++j) {
        const int col = ct * 256 + wc * 64 + j * 32 + r32;
        const float bv = bias[col];
#pragma unroll
        for (int q = 0; q < 4; ++q)
#pragma unroll
          for (int rr = 0; rr < 4; ++rr) {
            const int row = rt * 256 + wr * 128 + i * 32 + q * 8 + hi5 * 4 + rr;
            O[(size_t)row * ODIM + col] =
                __builtin_fmaf((float)acc[i][j][q * 4 + rr], s1, bv);
          }
      }
    }
  }
}

extern "C" void kernel_launch(void* const* d_in, const int* in_sizes, int n_in,
                              void* d_out, int out_size, void* d_ws, size_t ws_size,
                              hipStream_t stream) {
  (void)in_sizes; (void)n_in; (void)out_size;
  const int*   x32  = (const int*)d_in[0];
  const int*   w132 = (const int*)d_in[1];
  const float* b1   = (const float*)d_in[2];
  const int*   w232 = (const int*)d_in[3];
  const float* b2   = (const float*)d_in[4];
  const float* a1   = (const float*)d_in[5];
  const float* sreq = (const float*)d_in[6];
  const float* a2   = (const float*)d_in[7];
  float* out = (float*)d_out;

  const int M = 4 * 4096;                       // 16384 tokens
  const size_t WN = (size_t)H_DIM * D_DIM;      // 6,553,600 weights each
  constexpr int BT = 256;                       // token tile

  int8_t* w1p  = (int8_t*)d_ws;
  int8_t* w2p  = w1p + WN;
  int8_t* base = w2p + WN;

  // chunk M (multiple of 256) so packed-x chunk + q chunk fit in workspace
  size_t avail = ws_size > 2 * WN ? ws_size - 2 * WN : 0;
  size_t rows = avail / (size_t)(D_DIM + H_DIM);
  int Mc = (int)((rows / BT) * BT);
  if (Mc > M) Mc = M;
  if (Mc < BT) Mc = BT;

  k_packw<<<(int)(2 * WN / 4096), 256, 0, stream>>>(w132, w232, w1p, (long)WN);

  for (int m0 = 0; m0 < M; m0 += Mc) {
    const int mc = (M - m0 < Mc) ? (M - m0) : Mc;
    int8_t* xp = base;
    int8_t* q  = base + (size_t)Mc * D_DIM;
    const size_t nx = (size_t)mc * D_DIM;
    const int mt = mc / BT;
    k_pack<<<(int)(nx / 4096), 256, 0, stream>>>(x32 + (size_t)m0 * D_DIM, xp, (long)nx);
    // lin1: P=W1 (20 r-tiles), S=x (mt c-tiles); CFAST keeps W1 panel resident
    k_gemm256<D_DIM, H_DIM, true, true><<<20 * mt, 512, 0, stream>>>(
        w1p, xp, b1, a1, sreq, q, 20, mt);
    // lin2: P=q (mt r-tiles), S=W2 (5 c-tiles); RFAST keeps W2 panel resident
    k_gemm256<H_DIM, D_DIM, false, false><<<mt * 5, 512, 0, stream>>>(
        q, w2p, b2, a2, a2, out + (size_t)m0 * D_DIM, mt, 5);
  }
}

// Round 8
// 319.833 us; speedup vs baseline: 1.1413x; 1.1413x over previous
//
#include <hip/hip_runtime.h>
#include <stdint.h>
#include <math.h>

typedef __attribute__((ext_vector_type(4))) int i32x4;
typedef __attribute__((ext_vector_type(16))) int i32x16;
typedef __attribute__((ext_vector_type(4))) float f32x4;

constexpr int D_DIM = 1280;   // embedding dim (lin1 K, lin2 N)
constexpr int H_DIM = 5120;   // mlp dim      (lin1 N, lin2 K)

__device__ __forceinline__ void gload_lds16(const void* g, void* l) {
  __builtin_amdgcn_global_load_lds(
      (const __attribute__((address_space(1))) void*)g,
      (__attribute__((address_space(3))) void*)l,
      16, 0, 0);
}

// ---- pack int32 (sign-extended int8) -> int8 --------------------------------
__global__ void __launch_bounds__(256) k_packw(const int* __restrict__ s1,
                                               const int* __restrict__ s2,
                                               int8_t* __restrict__ out,
                                               long wn) {
  long i = ((long)blockIdx.x * 256 + threadIdx.x) * 16;
  const int* p = (i < wn) ? (s1 + i) : (s2 + (i - wn));
  i32x4 a = *(const i32x4*)(p);
  i32x4 b = *(const i32x4*)(p + 4);
  i32x4 c = *(const i32x4*)(p + 8);
  i32x4 d = *(const i32x4*)(p + 12);
  i32x4 r;
  r.x = (a.x & 255) | ((a.y & 255) << 8) | ((a.z & 255) << 16) | (a.w << 24);
  r.y = (b.x & 255) | ((b.y & 255) << 8) | ((b.z & 255) << 16) | (b.w << 24);
  r.z = (c.x & 255) | ((c.y & 255) << 8) | ((c.z & 255) << 16) | (c.w << 24);
  r.w = (d.x & 255) | ((d.y & 255) << 8) | ((d.z & 255) << 16) | (d.w << 24);
  *(i32x4*)(out + i) = r;
}

__global__ void __launch_bounds__(256) k_pack(const int* __restrict__ in,
                                              int8_t* __restrict__ out,
                                              long n) {
  long i = ((long)blockIdx.x * 256 + threadIdx.x) * 16;
  if (i >= n) return;
  const int* p = in + i;
  i32x4 a = *(const i32x4*)(p);
  i32x4 b = *(const i32x4*)(p + 4);
  i32x4 c = *(const i32x4*)(p + 8);
  i32x4 d = *(const i32x4*)(p + 12);
  i32x4 r;
  r.x = (a.x & 255) | ((a.y & 255) << 8) | ((a.z & 255) << 16) | (a.w << 24);
  r.y = (b.x & 255) | ((b.y & 255) << 8) | ((b.z & 255) << 16) | (b.w << 24);
  r.z = (c.x & 255) | ((c.y & 255) << 8) | ((c.z & 255) << 16) | (c.w << 24);
  r.w = (d.x & 255) | ((d.y & 255) << 8) | ((d.z & 255) << 16) | (d.w << 24);
  *(i32x4*)(out + i) = r;
}

// ---- fused int8 GEMM: 256x128 tile, BK=64, 4 waves, 2 blocks/CU -------------
// D[r][c] = sum_k P[r][k]*S[c][k]; P,S row-major ld=KDIM (NT GEMM).
// GELU=true  (lin1): P=W1 (r=h), S=x (c=token). sigmoid-GELU + requant ->
//            int8 Q[token][h] (ld ODIM) via swizzled 32KB LDS transpose.
// GELU=false (lin2): P=q (r=token), S=W2 (c=d). fp32 out row-major ld ODIM.
// GROUP_C: group 4 c-tiles (lin1: tokens); else group 4 r-tiles (lin2: tokens).
template <int KDIM, int ODIM, bool GELU, bool GROUP_C>
__global__ void __launch_bounds__(256, 2)
k_gemm(const int8_t* __restrict__ P, const int8_t* __restrict__ S,
       const float* __restrict__ bias, const float* __restrict__ ps1,
       const float* __restrict__ ps2, void* __restrict__ Cout,
       int rtiles, int ctiles) {
  constexpr int BKB = 64;
  constexpr int NT = KDIM / BKB;   // 20 (lin1) / 80 (lin2), both even
  // [A b0 16K][A b1 16K][B b0 8K][B b1 8K] = 48 KB; epilogue reuses [0,32K)
  __shared__ __align__(16) int8_t smem[49152];

  // ---- block mapping: bijective XCD chunk + token-4 grouping ----------------
  const int nwg = rtiles * ctiles;
  int rt, ct;
  {
    const int bid = blockIdx.x;
    const int q = nwg >> 3, r = nwg & 7, x = bid & 7, l = bid >> 3;
    const int swz = (x < r ? x * (q + 1) : r * (q + 1) + (x - r) * q) + l;
    if (GROUP_C && (ctiles & 3) == 0) {
      const int G = rtiles * 4, g = swz / G, rr = swz % G;
      rt = rr >> 2; ct = g * 4 + (rr & 3);
    } else if (!GROUP_C && (rtiles & 3) == 0) {
      const int G = ctiles * 4, g = swz / G, rr = swz % G;
      ct = rr >> 2; rt = g * 4 + (rr & 3);
    } else {
      rt = swz / ctiles; ct = swz % ctiles;
    }
  }

  const int tid = threadIdx.x;
  const int lane = tid & 63, wid = tid >> 6;
  const int wr = wid >> 1, wc = wid & 1;   // 2x2 waves: 128x64 out each
  const int r32 = lane & 31, hi5 = lane >> 5;

  // ---- staging: linear LDS dest, inverse-swizzled global src ----------------
  // dest slot d (16B): row=d>>2, sl=d&3; src in-row slot = sl ^ (row&3)
  const int srow = tid >> 2;                        // 0..63
  const int ssl  = ((tid & 3) ^ (srow & 3)) << 4;
  const int8_t* Pth = P + (size_t)(rt * 256 + srow) * KDIM + ssl;
  const int8_t* Sth = S + (size_t)(ct * 128 + srow) * KDIM + ssl;
  const int dT = tid * 16;

  auto STAGE = [&](int buf, int t) {   // A: 4 instr, B: 2 instr per thread
    const int8_t* ga = Pth + t * BKB;
    const int8_t* gb = Sth + t * BKB;
#pragma unroll
    for (int p = 0; p < 4; ++p)
      gload_lds16(ga + (size_t)(p * 64) * KDIM, smem + buf * 16384 + p * 4096 + dT);
#pragma unroll
    for (int p = 0; p < 2; ++p)
      gload_lds16(gb + (size_t)(p * 64) * KDIM,
                  smem + 32768 + buf * 8192 + p * 4096 + dT);
  };

  // ---- fragment offsets (conflict-free: slot = (2ks+hi5) ^ (r32&3)) ---------
  const int ksl = r32 & 3;
  const int ko0 = ((0 + hi5) ^ ksl) << 4;
  const int ko1 = ((2 + hi5) ^ ksl) << 4;
  const int rowA = (wr * 128 + r32) * 64;   // + i*2048 per 32-row frag
  const int rowB = (wc * 64 + r32) * 64;    // + j*2048

  i32x16 acc[4][2] = {};

  auto COMPUTE = [&](int buf) {
    const int8_t* Ab = smem + buf * 16384;
    const int8_t* Bb = smem + 32768 + buf * 8192;
#pragma unroll
    for (int ks = 0; ks < 2; ++ks) {
      const int ko = ks ? ko1 : ko0;
      i32x4 pf[4], sf[2];
#pragma unroll
      for (int i = 0; i < 4; ++i) pf[i] = *(const i32x4*)(Ab + rowA + i * 2048 + ko);
#pragma unroll
      for (int j = 0; j < 2; ++j) sf[j] = *(const i32x4*)(Bb + rowB + j * 2048 + ko);
      __builtin_amdgcn_s_setprio(1);
#pragma unroll
      for (int i = 0; i < 4; ++i)
#pragma unroll
        for (int j = 0; j < 2; ++j)
          acc[i][j] =
              __builtin_amdgcn_mfma_i32_32x32x32_i8(pf[i], sf[j], acc[i][j], 0, 0, 0);
      __builtin_amdgcn_s_setprio(0);
    }
  };

  // ---- main loop: simple 2-phase dbuf (2 blocks/CU cover the drains) --------
  STAGE(0, 0);
  __syncthreads();
#pragma unroll 1
  for (int t = 0; t < NT; t += 2) {
    STAGE(1, t + 1);
    COMPUTE(0);
    __syncthreads();
    if (t + 2 < NT) STAGE(0, t + 2);
    COMPUTE(1);
    __syncthreads();
  }

  // ---- epilogue -------------------------------------------------------------
  // 32x32 C/D: col = lane&31, row = (reg&3) + 8*(reg>>2) + 4*(lane>>5)
  const float s1 = *ps1;
  if constexpr (GELU) {
    const float rs = 1.0f / (*ps2);
    int8_t* Q = (int8_t*)Cout;
    int8_t* lb = smem;   // 32 KB: 128 tok x 256 h, swizzled 16B slots
#pragma unroll
    for (int i = 0; i < 4; ++i) {
#pragma unroll
      for (int qq = 0; qq < 4; ++qq) {
        const int hb = wr * 128 + i * 32 + qq * 8 + hi5 * 4;  // 4 consecutive h
        const f32x4 bv = *(const f32x4*)(bias + rt * 256 + hb);
#pragma unroll
        for (int j = 0; j < 2; ++j) {
          const int tok = wc * 64 + j * 32 + r32;
          uint32_t pk = 0;
#pragma unroll
          for (int rr = 0; rr < 4; ++rr) {
            const float h = __builtin_fmaf((float)acc[i][j][qq * 4 + rr], s1, bv[rr]);
            // sigmoid-GELU: h * sigma(1.702h); exact in both saturation tails
            const float e = __expf(-1.702f * h);
            const float g = h * __builtin_amdgcn_rcpf(1.0f + e);
            float qf = rintf(g * rs);
            qf = fminf(127.0f, fmaxf(-128.0f, qf));
            pk |= ((uint32_t)((int)qf & 255)) << (rr * 8);
          }
          const int sl = (hb >> 4) ^ (tok & 7) ^ ((tok & 24) >> 1);
          *(uint32_t*)(lb + tok * 256 + (sl << 4) + (hb & 12)) = pk;
        }
      }
    }
    __syncthreads();
    // readback: per instr 4 rows x 256B, fully coalesced dwordx4 stores
#pragma unroll
    for (int it = 0; it < 8; ++it) {
      const int row = it * 16 + (tid >> 4);
      const int sl = tid & 15;
      const int s2 = sl ^ (row & 7) ^ ((row & 24) >> 1);
      i32x4 v = *(const i32x4*)(lb + row * 256 + (s2 << 4));
      *(i32x4*)(Q + (size_t)(ct * 128 + row) * ODIM + rt * 256 + sl * 16) = v;
    }
  } else {
    float* O = (float*)Cout;
#pragma unroll
    for (int i = 0; i < 4; ++i) {
#pragma unroll
      for (int j = 0; j < 2; ++j) {
        const int col = ct * 128 + wc * 64 + j * 32 + r32;
        const float bv = bias[col];
#pragma unroll
        for (int qq = 0; qq < 4; ++qq)
#pragma unroll
          for (int rr = 0; rr < 4; ++rr) {
            const int row = rt * 256 + wr * 128 + i * 32 + qq * 8 + hi5 * 4 + rr;
            O[(size_t)row * ODIM + col] =
                __builtin_fmaf((float)acc[i][j][qq * 4 + rr], s1, bv);
          }
      }
    }
  }
}

extern "C" void kernel_launch(void* const* d_in, const int* in_sizes, int n_in,
                              void* d_out, int out_size, void* d_ws, size_t ws_size,
                              hipStream_t stream) {
  (void)in_sizes; (void)n_in; (void)out_size;
  const int*   x32  = (const int*)d_in[0];
  const int*   w132 = (const int*)d_in[1];
  const float* b1   = (const float*)d_in[2];
  const int*   w232 = (const int*)d_in[3];
  const float* b2   = (const float*)d_in[4];
  const float* a1   = (const float*)d_in[5];
  const float* sreq = (const float*)d_in[6];
  const float* a2   = (const float*)d_in[7];
  float* out = (float*)d_out;

  const int M = 4 * 4096;                       // 16384 tokens
  const size_t WN = (size_t)H_DIM * D_DIM;      // 6,553,600 weights each

  int8_t* w1p  = (int8_t*)d_ws;
  int8_t* w2p  = w1p + WN;
  int8_t* base = w2p + WN;

  // chunk M (prefer multiple of 1024 for grouped mappings; min 256)
  size_t avail = ws_size > 2 * WN ? ws_size - 2 * WN : 0;
  size_t rows = avail / (size_t)(D_DIM + H_DIM);
  int Mc = (int)((rows / 1024) * 1024);
  if (Mc < 1024) Mc = (int)((rows / 256) * 256);
  if (Mc < 256) Mc = 256;
  if (Mc > M) Mc = M;

  k_packw<<<(int)(2 * WN / 4096), 256, 0, stream>>>(w132, w232, w1p, (long)WN);

  for (int m0 = 0; m0 < M; m0 += Mc) {
    const int mc = (M - m0 < Mc) ? (M - m0) : Mc;
    int8_t* xp = base;
    int8_t* q  = base + (size_t)Mc * D_DIM;
    const size_t nx = (size_t)mc * D_DIM;
    k_pack<<<(int)(nx / 4096), 256, 0, stream>>>(x32 + (size_t)m0 * D_DIM, xp, (long)nx);
    // lin1: P=W1 (20 h-tiles of 256), S=x (mc/128 token-tiles); group tokens
    k_gemm<D_DIM, H_DIM, true, true><<<20 * (mc / 128), 256, 0, stream>>>(
        w1p, xp, b1, a1, sreq, q, 20, mc / 128);
    // lin2: P=q (mc/256 token-tiles), S=W2 (10 d-tiles of 128); group tokens
    k_gemm<H_DIM, D_DIM, false, false><<<(mc / 256) * 10, 256, 0, stream>>>(
        q, w2p, b2, a2, nullptr, out + (size_t)m0 * D_DIM, mc / 256, 10);
  }
}

// Round 9
// 284.374 us; speedup vs baseline: 1.2837x; 1.1247x over previous
//
#include <hip/hip_runtime.h>
#include <stdint.h>
#include <math.h>

typedef __attribute__((ext_vector_type(4))) int i32x4;
typedef __attribute__((ext_vector_type(16))) int i32x16;
typedef __attribute__((ext_vector_type(4))) float f32x4;

constexpr int D_DIM = 1280;   // embedding dim (lin1 K, lin2 N)
constexpr int H_DIM = 5120;   // mlp dim      (lin1 N, lin2 K)

__device__ __forceinline__ void gload_lds16(const void* g, void* l) {
  __builtin_amdgcn_global_load_lds(
      (const __attribute__((address_space(1))) void*)g,
      (__attribute__((address_space(3))) void*)l,
      16, 0, 0);
}

// ---- pack int32 (sign-extended int8) -> int8 --------------------------------
__global__ void __launch_bounds__(256) k_packw(const int* __restrict__ s1,
                                               const int* __restrict__ s2,
                                               int8_t* __restrict__ out,
                                               long wn) {
  long i = ((long)blockIdx.x * 256 + threadIdx.x) * 16;
  const int* p = (i < wn) ? (s1 + i) : (s2 + (i - wn));
  i32x4 a = *(const i32x4*)(p);
  i32x4 b = *(const i32x4*)(p + 4);
  i32x4 c = *(const i32x4*)(p + 8);
  i32x4 d = *(const i32x4*)(p + 12);
  i32x4 r;
  r.x = (a.x & 255) | ((a.y & 255) << 8) | ((a.z & 255) << 16) | (a.w << 24);
  r.y = (b.x & 255) | ((b.y & 255) << 8) | ((b.z & 255) << 16) | (b.w << 24);
  r.z = (c.x & 255) | ((c.y & 255) << 8) | ((c.z & 255) << 16) | (c.w << 24);
  r.w = (d.x & 255) | ((d.y & 255) << 8) | ((d.z & 255) << 16) | (d.w << 24);
  *(i32x4*)(out + i) = r;
}

__global__ void __launch_bounds__(256) k_pack(const int* __restrict__ in,
                                              int8_t* __restrict__ out,
                                              long n) {
  long i = ((long)blockIdx.x * 256 + threadIdx.x) * 16;
  if (i >= n) return;
  const int* p = in + i;
  i32x4 a = *(const i32x4*)(p);
  i32x4 b = *(const i32x4*)(p + 4);
  i32x4 c = *(const i32x4*)(p + 8);
  i32x4 d = *(const i32x4*)(p + 12);
  i32x4 r;
  r.x = (a.x & 255) | ((a.y & 255) << 8) | ((a.z & 255) << 16) | (a.w << 24);
  r.y = (b.x & 255) | ((b.y & 255) << 8) | ((b.z & 255) << 16) | (b.w << 24);
  r.z = (c.x & 255) | ((c.y & 255) << 8) | ((c.z & 255) << 16) | (c.w << 24);
  r.w = (d.x & 255) | ((d.y & 255) << 8) | ((d.z & 255) << 16) | (d.w << 24);
  *(i32x4*)(out + i) = r;
}

// ---- fused int8 GEMM: 128x128 tile, BK=128, 32x32x32 MFMA, static dbuf ------
// A [Mt*128, KDIM] i8 row-major; B [NDIM, KDIM] i8 row-major (NT GEMM).
// GELU=true : transposed acc (mfma(b,a)); sigmoid-GELU + requant -> packed
//             dwords -> pad-132 LDS transpose -> coalesced dwordx4 stores.
// GELU=false: fp32 out = acc*s1 + bias, coalesced f32 stores.
template <int KDIM, int NDIM, bool GELU>
__global__ void __launch_bounds__(256, 2)
k_gemm(const int8_t* __restrict__ A, const int8_t* __restrict__ B,
       const float* __restrict__ bias, const float* __restrict__ ps1,
       const float* __restrict__ ps2, void* __restrict__ Cout, int Mtiles) {
  constexpr int BM = 128, BN = 128, BKB = 128;
  constexpr int NT = KDIM / BKB;   // 10 (lin1) / 40 (lin2); both even
  constexpr int BNC = NDIM / BN;   // 40 / 10
  constexpr int G = BNC * 4;

  // layout: [A buf0 16K][A buf1 16K][B buf0 16K][B buf1 16K]
  __shared__ __align__(16) int8_t smem[4 * 16384];

  // ---- block mapping: bijective XCD chunk + 4-row grouping (r4-verified) ----
  const int nwg = Mtiles * BNC;
  int bm, bn;
  {
    const int bid = blockIdx.x;
    const int q = nwg >> 3, r = nwg & 7, x = bid & 7, l = bid >> 3;
    const int swz = (x < r ? x * (q + 1) : r * (q + 1) + (x - r) * q) + l;
    if ((Mtiles & 3) == 0) {
      const int g = swz / G, rr = swz % G;
      bn = rr >> 2;
      bm = g * 4 + (rr & 3);
    } else {
      bn = swz % BNC;
      bm = swz / BNC;
    }
  }

  const int tid = threadIdx.x;
  const int lane = tid & 63, wid = tid >> 6;
  const int wr = wid >> 1, wc = wid & 1;  // 2x2 waves, 64x64 out each

  // ---- staging: linear LDS dest, inverse-swizzled global source -------------
  const int srow = tid >> 3;                       // 0..31
  const int soff = (((tid & 7) ^ (srow & 7)) << 4);
  const int8_t* Ath = A + (size_t)(bm * BM + srow) * KDIM + soff;
  const int8_t* Bth = B + (size_t)(bn * BN + srow) * KDIM + soff;
  const int dT = tid * 16;

  auto STAGE = [&](int boff, const int8_t* ga, const int8_t* gb) {
#pragma unroll
    for (int p = 0; p < 4; ++p)
      gload_lds16(ga + (size_t)(p * 32) * KDIM, smem + boff + dT + p * 4096);
#pragma unroll
    for (int p = 0; p < 4; ++p)
      gload_lds16(gb + (size_t)(p * 32) * KDIM,
                  smem + 32768 + boff + dT + p * 4096);
  };

  // ---- fragment addresses (32x32x32: row = lane&31, k = (lane>>5)*16+b) -----
  const int r32 = lane & 31, hi5 = lane >> 5;
  const int fsw = (lane & 7) << 4;   // row&7 == lane&7 (row offsets are mult-8)
  const int kq = hi5 << 4;
  const int8_t* aP[4];
  const int8_t* bP[4];
#pragma unroll
  for (int ks = 0; ks < 4; ++ks) {
    const int koff = (ks * 32 + kq) ^ fsw;
    aP[ks] = smem + (wr * 64 + r32) * BKB + koff;
    bP[ks] = smem + 32768 + (wc * 64 + r32) * BKB + koff;
  }

  i32x16 acc[2][2] = {};

  auto COMPUTE = [&](int boff) {
#pragma unroll
    for (int ks = 0; ks < 4; ++ks) {
      i32x4 a0 = *(const i32x4*)(aP[ks] + boff);
      i32x4 a1 = *(const i32x4*)(aP[ks] + boff + 4096);
      i32x4 b0 = *(const i32x4*)(bP[ks] + boff);
      i32x4 b1 = *(const i32x4*)(bP[ks] + boff + 4096);
      if constexpr (GELU) {  // transposed: acc[n][m], D-row = h, D-col = token
        acc[0][0] = __builtin_amdgcn_mfma_i32_32x32x32_i8(b0, a0, acc[0][0], 0, 0, 0);
        acc[0][1] = __builtin_amdgcn_mfma_i32_32x32x32_i8(b0, a1, acc[0][1], 0, 0, 0);
        acc[1][0] = __builtin_amdgcn_mfma_i32_32x32x32_i8(b1, a0, acc[1][0], 0, 0, 0);
        acc[1][1] = __builtin_amdgcn_mfma_i32_32x32x32_i8(b1, a1, acc[1][1], 0, 0, 0);
      } else {               // normal: acc[m][n], D-row = token, D-col = d
        acc[0][0] = __builtin_amdgcn_mfma_i32_32x32x32_i8(a0, b0, acc[0][0], 0, 0, 0);
        acc[0][1] = __builtin_amdgcn_mfma_i32_32x32x32_i8(a0, b1, acc[0][1], 0, 0, 0);
        acc[1][0] = __builtin_amdgcn_mfma_i32_32x32x32_i8(a1, b0, acc[1][0], 0, 0, 0);
        acc[1][1] = __builtin_amdgcn_mfma_i32_32x32x32_i8(a1, b1, acc[1][1], 0, 0, 0);
      }
    }
  };

  // ---- main loop: unroll-2, static buffer offsets, 1 barrier per tile -------
  STAGE(0, Ath, Bth);
  __syncthreads();
  const int8_t* gA = Ath + BKB;
  const int8_t* gB = Bth + BKB;
#pragma unroll 1
  for (int t = 0; t < NT; t += 2) {
    STAGE(16384, gA, gB);          // tile t+1 -> buf1
    COMPUTE(0);                    // tile t from buf0
    __syncthreads();               // drains vmcnt+lgkm: buf1 ready, buf0 free
    if (t + 2 < NT) STAGE(0, gA + BKB, gB + BKB);  // tile t+2 -> buf0
    COMPUTE(16384);                // tile t+1 from buf1
    __syncthreads();
    gA += 2 * BKB;
    gB += 2 * BKB;
  }

  // ---- epilogue -------------------------------------------------------------
  // 32x32 C/D layout: col = lane&31, row = (reg&3) + 8*(reg>>2) + 4*(lane>>5)
  if constexpr (GELU) {
    const float s1 = *ps1;
    const float rs = 1.0f / (*ps2);
    int8_t* Q = (int8_t*)Cout;
    // pad-132 transpose tile: 128 tok rows x (128 h + 4 pad) bytes = 16.9 KB
    // bank(tok,0) = tok*33 % 32 = tok % 32 -> 32 writes hit 32 distinct banks
    int8_t* lb = smem;
#pragma unroll
    for (int n = 0; n < 2; ++n) {
#pragma unroll
      for (int q = 0; q < 4; ++q) {
        const int hl = wc * 64 + n * 32 + q * 8 + hi5 * 4;  // local h base
        const f32x4 bv = *(const f32x4*)(bias + bn * BN + hl);
#pragma unroll
        for (int m = 0; m < 2; ++m) {
          const int tok = wr * 64 + m * 32 + r32;           // local token
          uint32_t pk = 0;
#pragma unroll
          for (int rr = 0; rr < 4; ++rr) {
            const float h = __builtin_fmaf((float)acc[n][m][q * 4 + rr], s1, bv[rr]);
            // sigmoid-GELU: h * sigma(1.702h); exact in both saturation tails
            const float e = __expf(-1.702f * h);
            const float g = h * __builtin_amdgcn_rcpf(1.0f + e);
            float qf = rintf(g * rs);
            qf = fminf(127.0f, fmaxf(-128.0f, qf));
            pk |= ((uint32_t)((int)qf & 255)) << (rr * 8);
          }
          *(uint32_t*)(lb + tok * 132 + hl) = pk;
        }
      }
    }
    __syncthreads();
    // readback: 4-aligned b32 reads (2-way max), coalesced dwordx4 stores
#pragma unroll
    for (int it = 0; it < 4; ++it) {
      const int row = it * 32 + (tid >> 3);
      const int sl = tid & 7;
      const int8_t* rp = lb + row * 132 + sl * 16;
      i32x4 v;
      v.x = *(const int*)(rp);
      v.y = *(const int*)(rp + 4);
      v.z = *(const int*)(rp + 8);
      v.w = *(const int*)(rp + 12);
      *(i32x4*)(Q + (size_t)(bm * BM + row) * NDIM + bn * BN + sl * 16) = v;
    }
  } else {
    const float s1 = *ps1;
    float* O = (float*)Cout;
    const int colb = bn * BN + wc * 64 + r32;
#pragma unroll
    for (int n = 0; n < 2; ++n) {
      const int col = colb + n * 32;
      const float bv = bias[col];
#pragma unroll
      for (int m = 0; m < 2; ++m) {
        const int rowb = bm * BM + wr * 64 + m * 32 + hi5 * 4;
#pragma unroll
        for (int q = 0; q < 4; ++q)
#pragma unroll
          for (int rr = 0; rr < 4; ++rr) {
            const int row = rowb + q * 8 + rr;
            O[(size_t)row * NDIM + col] =
                __builtin_fmaf((float)acc[m][n][q * 4 + rr], s1, bv);
          }
      }
    }
  }
}

extern "C" void kernel_launch(void* const* d_in, const int* in_sizes, int n_in,
                              void* d_out, int out_size, void* d_ws, size_t ws_size,
                              hipStream_t stream) {
  (void)in_sizes; (void)n_in; (void)out_size;
  const int*   x32  = (const int*)d_in[0];
  const int*   w132 = (const int*)d_in[1];
  const float* b1   = (const float*)d_in[2];
  const int*   w232 = (const int*)d_in[3];
  const float* b2   = (const float*)d_in[4];
  const float* a1   = (const float*)d_in[5];
  const float* sreq = (const float*)d_in[6];
  const float* a2   = (const float*)d_in[7];
  float* out = (float*)d_out;

  const int M = 4 * 4096;                       // 16384 tokens
  const size_t WN = (size_t)H_DIM * D_DIM;      // 6,553,600 weights each
  constexpr int BM = 128, BN = 128;

  int8_t* w1p  = (int8_t*)d_ws;
  int8_t* w2p  = w1p + WN;
  int8_t* base = w2p + WN;

  // chunk M (multiple of 128) so packed-x chunk + q chunk fit in workspace
  size_t avail = ws_size > 2 * WN ? ws_size - 2 * WN : 0;
  size_t rows = avail / (size_t)(D_DIM + H_DIM);
  int Mc = (int)((rows / BM) * BM);
  if (Mc > M) Mc = M;
  if (Mc < BM) Mc = BM;

  k_packw<<<(int)(2 * WN / 4096), 256, 0, stream>>>(w132, w232, w1p, (long)WN);

  for (int m0 = 0; m0 < M; m0 += Mc) {
    const int mc = (M - m0 < Mc) ? (M - m0) : Mc;
    int8_t* xp = base;
    int8_t* q  = base + (size_t)Mc * D_DIM;
    const size_t nx = (size_t)mc * D_DIM;
    const int mt = mc / BM;
    k_pack<<<(int)(nx / 4096), 256, 0, stream>>>(x32 + (size_t)m0 * D_DIM, xp, (long)nx);
    k_gemm<D_DIM, H_DIM, true><<<mt * (H_DIM / BN), 256, 0, stream>>>(
        xp, w1p, b1, a1, sreq, q, mt);
    k_gemm<H_DIM, D_DIM, false><<<mt * (D_DIM / BN), 256, 0, stream>>>(
        q, w2p, b2, a2, nullptr, out + (size_t)m0 * D_DIM, mt);
  }
}